// Round 9
// baseline (1712.029 us; speedup 1.0000x reference)
//
#include <hip/hip_runtime.h>
#include <hip/hip_fp16.h>

// GCNII on MI355X. fp32 compute, fp16 storage for the gathered state.
//   CSR build (bucket-local, R7): bhist -> bscan -> bucket -> finalize
//     (finalize now stores src pre-scaled to BYTE offsets: src*256)
//   Wc[i] = theta_i*conv_w[i] + (1-theta_i)*I  (absorbs identity-mapping mix)
//   h0 = x@W_in + b_in (fp16)
//   8x fused layer: wave-per-row CSR gather (2 edges/instr, 16 in flight,
//     v_pk_fma_f32 accum) -> support -> LDS -> @Wc (pk_fma) -> relu -> fp16
//   out = h@W_out + b_out
// R9 change: phase-A VALU cut ~2x (no csr selects, packed fma, byte-offset src).

constexpr int NN = 100000;
constexpr int EE = 3200000;
constexpr int NB = 256;          // buckets, dst>>9 (512 nodes each)
constexpr int NBUCK = (NN + 511) / 512;

struct alignas(8) Half4 { __half2 lo, hi; };
typedef float f32x2 __attribute__((ext_vector_type(2)));

// ---------------- k1: bucket histogram (LDS-aggregated) ----------------
__global__ __launch_bounds__(256) void bhist_kernel(const int* __restrict__ dst,
                                                    int* __restrict__ bhist, int e) {
    __shared__ int lh[NB];
    lh[threadIdx.x] = 0;
    __syncthreads();
    for (int i = blockIdx.x * 256 + threadIdx.x; i < e; i += gridDim.x * 256)
        atomicAdd(&lh[dst[i] >> 9], 1);
    __syncthreads();
    if (lh[threadIdx.x]) atomicAdd(&bhist[threadIdx.x], lh[threadIdx.x]);
}

// ---------------- k2: bucket scan ----------------
__global__ void bscan_kernel(const int* __restrict__ bhist, int* __restrict__ bbase,
                             int* __restrict__ bcur, int* __restrict__ row_ptr) {
    if (threadIdx.x == 0) {
        int s = 0;
        for (int b = 0; b < NB; ++b) { bbase[b] = s; bcur[b] = s; s += bhist[b]; }
        bbase[NB] = s;
        row_ptr[NN] = s;
    }
}

// ---------------- k3: chunk counting-sort into buckets ----------------
__global__ __launch_bounds__(256, 3) void bucket_kernel(const int* __restrict__ src,
                                                        const int* __restrict__ dst,
                                                        const float* __restrict__ val,
                                                        int* __restrict__ bcur,
                                                        int2* __restrict__ bsorted,
                                                        int* __restrict__ bdst, int e_total) {
    __shared__ int bin_cnt[NB], bin_excl[NB], bin_gbase[NB], bin_cur[NB];
    __shared__ int2 s_ed[4096];   // 32KB
    __shared__ int  s_dp[4096];   // 16KB
    const int tid = threadIdx.x;
    const int e_base = blockIdx.x * 4096;
    const int count = min(4096, e_total - e_base);
    bin_cnt[tid] = 0;
    __syncthreads();
    #pragma unroll
    for (int i = 0; i < 16; ++i) {
        int idx = e_base + i * 256 + tid;
        if (idx < e_total) atomicAdd(&bin_cnt[dst[idx] >> 9], 1);
    }
    __syncthreads();
    if (tid == 0) {
        int s = 0;
        for (int b = 0; b < NB; ++b) { bin_excl[b] = s; s += bin_cnt[b]; }
    }
    __syncthreads();
    bin_gbase[tid] = atomicAdd(&bcur[tid], bin_cnt[tid]);
    bin_cur[tid] = bin_excl[tid];
    __syncthreads();
    #pragma unroll
    for (int i = 0; i < 16; ++i) {
        int idx = e_base + i * 256 + tid;
        if (idx < e_total) {
            int d = dst[idx];
            int pos = atomicAdd(&bin_cur[d >> 9], 1);
            s_ed[pos] = make_int2(src[idx], __float_as_int(val[idx]));
            s_dp[pos] = d;
        }
    }
    __syncthreads();
    for (int pos = tid; pos < count; pos += 256) {
        int d = s_dp[pos], b = d >> 9;
        int g = bin_gbase[b] + (pos - bin_excl[b]);
        bsorted[g] = s_ed[pos];
        bdst[g] = d;
    }
}

// ---------------- k4: per-bucket finalize (row_ptr + csr, src -> byte off) ----
__global__ __launch_bounds__(512) void finalize_kernel(const int2* __restrict__ bsorted,
                                                       const int* __restrict__ bdst,
                                                       const int* __restrict__ bbase,
                                                       int* __restrict__ row_ptr,
                                                       int2* __restrict__ csr) {
    __shared__ int hist[512], cur[512], wsum[8];
    const int tid = threadIdx.x, lane = tid & 63, wid = tid >> 6;
    const int b = blockIdx.x;
    const int n0 = b << 9;
    const int nodes = min(512, NN - n0);
    const int es = bbase[b], ee = bbase[b + 1], cnt = ee - es;
    hist[tid] = 0;
    __syncthreads();
    for (int i = tid; i < cnt; i += 512) atomicAdd(&hist[bdst[es + i] - n0], 1);
    __syncthreads();
    int v = hist[tid];
    int x = v;
    #pragma unroll
    for (int d = 1; d < 64; d <<= 1) {
        int y = __shfl_up(x, (unsigned)d);
        if (lane >= d) x += y;
    }
    if (lane == 63) wsum[wid] = x;
    __syncthreads();
    if (tid == 0) {
        int s = 0;
        for (int w = 0; w < 8; ++w) { int t2 = wsum[w]; wsum[w] = s; s += t2; }
    }
    __syncthreads();
    int excl = x - v + wsum[wid];
    cur[tid] = excl;
    if (tid < nodes) row_ptr[n0 + tid] = es + excl;
    __syncthreads();
    for (int i = tid; i < cnt; i += 512) {
        int d = bdst[es + i];
        int p = atomicAdd(&cur[d - n0], 1);
        int2 ev = bsorted[es + i];
        ev.x <<= 8;                       // src row -> byte offset (256 B/row fp16)
        csr[es + p] = ev;
    }
}

// ---------------- Wc = theta*W + (1-theta)*I ----------------
__global__ void prep_wc_kernel(const float* __restrict__ conv_w, float* __restrict__ Wc) {
    int layer = blockIdx.y;
    int idx = blockIdx.x * 256 + threadIdx.x;          // 0..16383
    float theta = logf(0.5f / (float)(layer + 1) + 1.0f);
    int k = idx >> 7, j = idx & 127;
    float w = conv_w[layer * 16384 + idx];
    Wc[layer * 16384 + idx] = theta * w + ((k == j) ? (1.0f - theta) : 0.0f);
}

// ---------------- fc_in: h0 = x@W_in + b_in (fp16 out) ----------------
__global__ __launch_bounds__(256, 2) void fc_in_kernel(const float* __restrict__ x,
                                                       const float* __restrict__ W,
                                                       const float* __restrict__ b,
                                                       __half* __restrict__ h0) {
    __shared__ float sW[128 * 128];   // 64KB
    __shared__ float sA[32 * 128];    // 16KB
    const int tid = threadIdx.x;
    #pragma unroll
    for (int t = 0; t < 16; ++t)
        ((float4*)sW)[t * 256 + tid] = ((const float4*)W)[t * 256 + tid];
    const float4* xs = (const float4*)(x + (size_t)blockIdx.x * 32 * 128);
    #pragma unroll
    for (int t = 0; t < 4; ++t)
        ((float4*)sA)[t * 256 + tid] = xs[t * 256 + tid];
    __syncthreads();

    const int rowg = tid >> 5, colg = tid & 31;
    float4 bias = ((const float4*)b)[colg];
    float acc[4][4];
    #pragma unroll
    for (int r = 0; r < 4; ++r) { acc[r][0] = bias.x; acc[r][1] = bias.y; acc[r][2] = bias.z; acc[r][3] = bias.w; }

    for (int k = 0; k < 128; ++k) {
        float4 w = *(const float4*)&sW[k * 128 + (colg << 2)];
        float s[4];
        #pragma unroll
        for (int r = 0; r < 4; ++r) s[r] = sA[((rowg << 2) + r) * 128 + k];
        #pragma unroll
        for (int r = 0; r < 4; ++r) {
            acc[r][0] = fmaf(s[r], w.x, acc[r][0]);
            acc[r][1] = fmaf(s[r], w.y, acc[r][1]);
            acc[r][2] = fmaf(s[r], w.z, acc[r][2]);
            acc[r][3] = fmaf(s[r], w.w, acc[r][3]);
        }
    }
    const int row0 = blockIdx.x * 32;
    #pragma unroll
    for (int r = 0; r < 4; ++r) {
        Half4 o;
        o.lo = __floats2half2_rn(acc[r][0], acc[r][1]);
        o.hi = __floats2half2_rn(acc[r][2], acc[r][3]);
        *(Half4*)(h0 + ((size_t)(row0 + (rowg << 2) + r) << 7) + (colg << 2)) = o;
    }
}

#define FMA4(A0, A1, PV, G) { \
    float v_ = __int_as_float((PV).y); \
    f32x2 vv_ = {v_, v_}; \
    float2 lo_ = __half22float2((G).lo), hi_ = __half22float2((G).hi); \
    f32x2 gl_ = {lo_.x, lo_.y}, gh_ = {hi_.x, hi_.y}; \
    A0 += vv_ * gl_; \
    A1 += vv_ * gh_; }

// ---------------- fused layer ----------------
// Phase A: one wave per row; 2 edges per VMEM instr (half-wave each, Half4/lane),
//          16 edges in flight, csr loaded per-half-wave (no selects),
//          byte-offset src, v_pk_fma_f32 accum, shfl-combine.
// Phase B: S (LDS fp32, 16KB) @ Wc (global fp32, L2-hot, pk_fma) -> relu -> fp16.
__global__ __launch_bounds__(256, 8) void layer_kernel(const __half* __restrict__ h,
                                                       const __half* __restrict__ h0,
                                                       const int2* __restrict__ csr,
                                                       const int* __restrict__ row_ptr,
                                                       const float* __restrict__ Wc,
                                                       __half* __restrict__ hn) {
    __shared__ float sS[32 * 128];    // 16KB
    const int tid = threadIdx.x;
    const int wid = tid >> 6, lane = tid & 63;
    const int sub = lane >> 5;              // which edge of the pair
    const int q4 = (lane & 31) << 2;        // half index within the 128-wide row
    const int q4b = q4 << 1;                // byte offset of the Half4
    const char* hb = (const char*)h;
    const char* h0b = (const char*)h0;
    const int row0 = blockIdx.x * 32;
    const int rb = __builtin_amdgcn_readfirstlane(row0 + wid * 8);

    for (int rr = 0; rr < 8; ++rr) {
        const int r = rb + rr;
        const int e0 = row_ptr[r], e1 = row_ptr[r + 1];
        f32x2 aA0 = {0.f, 0.f}, aA1 = {0.f, 0.f};
        f32x2 aB0 = {0.f, 0.f}, aB1 = {0.f, 0.f};
        int e = e0;
        for (; e + 16 <= e1; e += 16) {
            int2 p0 = csr[e + sub + 0];
            int2 p1 = csr[e + sub + 2];
            int2 p2 = csr[e + sub + 4];
            int2 p3 = csr[e + sub + 6];
            int2 p4 = csr[e + sub + 8];
            int2 p5 = csr[e + sub + 10];
            int2 p6 = csr[e + sub + 12];
            int2 p7 = csr[e + sub + 14];
            Half4 g0 = *(const Half4*)(hb + (unsigned)(p0.x + q4b));
            Half4 g1 = *(const Half4*)(hb + (unsigned)(p1.x + q4b));
            Half4 g2 = *(const Half4*)(hb + (unsigned)(p2.x + q4b));
            Half4 g3 = *(const Half4*)(hb + (unsigned)(p3.x + q4b));
            Half4 g4 = *(const Half4*)(hb + (unsigned)(p4.x + q4b));
            Half4 g5 = *(const Half4*)(hb + (unsigned)(p5.x + q4b));
            Half4 g6 = *(const Half4*)(hb + (unsigned)(p6.x + q4b));
            Half4 g7 = *(const Half4*)(hb + (unsigned)(p7.x + q4b));
            FMA4(aA0, aA1, p0, g0); FMA4(aB0, aB1, p1, g1);
            FMA4(aA0, aA1, p2, g2); FMA4(aB0, aB1, p3, g3);
            FMA4(aA0, aA1, p4, g4); FMA4(aB0, aB1, p5, g5);
            FMA4(aA0, aA1, p6, g6); FMA4(aB0, aB1, p7, g7);
        }
        if (e < e1) {                       // one masked 16-wide tail block
            #pragma unroll
            for (int k = 0; k < 8; ++k) {
                int idx = e + 2 * k + sub;
                int2 p = csr[(idx < e1) ? idx : (e1 - 1)];
                if (idx >= e1) p.y = 0;     // zero weight, keep clamped (valid) src
                Half4 g = *(const Half4*)(hb + (unsigned)(p.x + q4b));
                if (k & 1) { FMA4(aB0, aB1, p, g); }
                else       { FMA4(aA0, aA1, p, g); }
            }
        }
        f32x2 a0 = aA0 + aB0, a1 = aA1 + aB1;
        float4 acc = make_float4(a0.x, a0.y, a1.x, a1.y);
        acc.x += __shfl_xor(acc.x, 32);
        acc.y += __shfl_xor(acc.y, 32);
        acc.z += __shfl_xor(acc.z, 32);
        acc.w += __shfl_xor(acc.w, 32);
        if (sub == 0) {
            Half4 q = *(const Half4*)(h0b + ((size_t)r << 8) + q4b);
            float2 a = __half22float2(q.lo), c = __half22float2(q.hi);
            float4 sv;
            sv.x = 0.9f * acc.x + 0.1f * a.x;
            sv.y = 0.9f * acc.y + 0.1f * a.y;
            sv.z = 0.9f * acc.z + 0.1f * c.x;
            sv.w = 0.9f * acc.w + 0.1f * c.y;
            *(float4*)&sS[(wid * 8 + rr) * 128 + q4] = sv;
        }
    }
    __syncthreads();

    // Phase B: out = S @ Wc, relu, fp16 store. Wc from global (64KB, L1/L2-hot).
    const int rowg = tid >> 5, colg = tid & 31;
    const float* wp = Wc + (colg << 2);
    f32x2 acc2[4][2] = {};
    for (int k = 0; k < 128; k += 2) {
        float4 w0 = *(const float4*)(wp + ((size_t)k << 7));
        float4 w1 = *(const float4*)(wp + ((size_t)(k + 1) << 7));
        f32x2 w0a = {w0.x, w0.y}, w0b = {w0.z, w0.w};
        f32x2 w1a = {w1.x, w1.y}, w1b = {w1.z, w1.w};
        #pragma unroll
        for (int r = 0; r < 4; ++r) {
            float s0 = sS[((rowg << 2) + r) * 128 + k];
            float s1 = sS[((rowg << 2) + r) * 128 + k + 1];
            f32x2 s0v = {s0, s0}, s1v = {s1, s1};
            acc2[r][0] += s0v * w0a;
            acc2[r][1] += s0v * w0b;
            acc2[r][0] += s1v * w1a;
            acc2[r][1] += s1v * w1b;
        }
    }
    #pragma unroll
    for (int r = 0; r < 4; ++r) {
        Half4 o;
        o.lo = __floats2half2_rn(fmaxf(acc2[r][0].x, 0.f), fmaxf(acc2[r][0].y, 0.f));
        o.hi = __floats2half2_rn(fmaxf(acc2[r][1].x, 0.f), fmaxf(acc2[r][1].y, 0.f));
        *(Half4*)(hn + ((size_t)(row0 + (rowg << 2) + r) << 7) + (colg << 2)) = o;
    }
}

// ---------------- fc_out: out = h(fp16)@W_out + b_out ----------------
__global__ __launch_bounds__(256, 3) void fc_out_kernel(const __half* __restrict__ h,
                                                        const float* __restrict__ W,
                                                        const float* __restrict__ b,
                                                        float* __restrict__ out, int n) {
    __shared__ float sW[128 * 40];    // 20KB
    __shared__ float sA[64 * 128];    // 32KB
    const int tid = threadIdx.x;
    #pragma unroll
    for (int t = 0; t < 5; ++t)
        ((float4*)sW)[t * 256 + tid] = ((const float4*)W)[t * 256 + tid];
    const int row0 = blockIdx.x * 64;
    #pragma unroll
    for (int t = 0; t < 8; ++t) {
        int idx = t * 256 + tid;              // 4-half chunk index, 2048 total
        int row = idx >> 5;                   // 32 chunks per 128-feat row
        int gr = row0 + row;
        float4 v = make_float4(0.f, 0.f, 0.f, 0.f);
        if (gr < n) {
            Half4 q = *(const Half4*)(h + ((size_t)gr << 7) + ((idx & 31) << 2));
            float2 a = __half22float2(q.lo), c = __half22float2(q.hi);
            v = make_float4(a.x, a.y, c.x, c.y);
        }
        *(float4*)&sA[row * 128 + ((idx & 31) << 2)] = v;
    }
    __syncthreads();

    const int rowg = tid >> 3;   // 32 groups x 2 rows
    const int colg = tid & 7;    // 8 groups x 5 cols
    float acc[2][5];
    #pragma unroll
    for (int c = 0; c < 5; ++c) {
        float bb = b[colg * 5 + c];
        acc[0][c] = bb; acc[1][c] = bb;
    }
    for (int k = 0; k < 128; ++k) {
        float s0 = sA[(rowg * 2 + 0) * 128 + k];
        float s1 = sA[(rowg * 2 + 1) * 128 + k];
        #pragma unroll
        for (int c = 0; c < 5; ++c) {
            float w = sW[k * 40 + colg * 5 + c];
            acc[0][c] = fmaf(s0, w, acc[0][c]);
            acc[1][c] = fmaf(s1, w, acc[1][c]);
        }
    }
    #pragma unroll
    for (int rr = 0; rr < 2; ++rr) {
        int r = row0 + rowg * 2 + rr;
        if (r < n) {
            #pragma unroll
            for (int c = 0; c < 5; ++c)
                out[(size_t)r * 40 + colg * 5 + c] = acc[rr][c];
        }
    }
}

extern "C" void kernel_launch(void* const* d_in, const int* in_sizes, int n_in,
                              void* d_out, int out_size, void* d_ws, size_t ws_size,
                              hipStream_t stream) {
    const float* x      = (const float*)d_in[0];
    const int*   esrc   = (const int*)d_in[1];
    const int*   edst   = (const int*)d_in[2];
    const float* eval   = (const float*)d_in[3];
    const float* W_in   = (const float*)d_in[4];
    const float* b_in   = (const float*)d_in[5];
    const float* conv_w = (const float*)d_in[6];
    const float* W_out  = (const float*)d_in[7];
    const float* b_out  = (const float*)d_in[8];
    float* out = (float*)d_out;

    // workspace carve-up (~142 MB total)
    __half* h0     = (__half*)d_ws;
    __half* hA     = h0 + (size_t)NN * 128;
    __half* hB     = hA + (size_t)NN * 128;
    float*  Wc     = (float*)(hB + (size_t)NN * 128);
    int*   row_ptr = (int*)(Wc + 8 * 128 * 128);          // NN+2 ints
    int*   bhist   = row_ptr + (NN + 2);                  // 256
    int*   bbase   = bhist + NB;                          // NB+1 (padded even)
    int*   bcur    = bbase + (NB + 2);                    // 256
    int2*  csr     = (int2*)(bcur + NB);                  // EE int2 (8B-aligned)
    int2*  bsorted = csr + EE;                            // EE int2
    int*   bdst    = (int*)(bsorted + EE);                // EE ints

    // --- CSR build (bucket-local) ---
    hipMemsetAsync(bhist, 0, NB * sizeof(int), stream);
    bhist_kernel<<<1024, 256, 0, stream>>>(edst, bhist, EE);
    bscan_kernel<<<1, 64, 0, stream>>>(bhist, bbase, bcur, row_ptr);
    bucket_kernel<<<(EE + 4095) / 4096, 256, 0, stream>>>(esrc, edst, eval, bcur,
                                                          bsorted, bdst, EE);
    finalize_kernel<<<NBUCK, 512, 0, stream>>>(bsorted, bdst, bbase, row_ptr, csr);

    // --- weights prep ---
    prep_wc_kernel<<<dim3(64, 8), 256, 0, stream>>>(conv_w, Wc);

    // --- fc_in ---
    fc_in_kernel<<<NN / 32, 256, 0, stream>>>(x, W_in, b_in, h0);

    // --- 8 fused layers, ping-pong hA/hB ---
    const __half* hin = h0;
    __half* hout = hA;
    for (int i = 0; i < 8; ++i) {
        layer_kernel<<<NN / 32, 256, 0, stream>>>(hin, h0, csr, row_ptr, Wc + i * 16384, hout);
        hin = hout;
        hout = (hout == hA) ? hB : hA;
    }

    // --- fc_out ---
    fc_out_kernel<<<(NN + 63) / 64, 256, 0, stream>>>(hin, W_out, b_out, out, NN);
}

// Round 10
// 1409.246 us; speedup vs baseline: 1.2149x; 1.2149x over previous
//
#include <hip/hip_runtime.h>
#include <hip/hip_fp16.h>

// GCNII on MI355X. fp32 compute, fp16 storage for the gathered state.
//   CSR build (bucket-local): bhist -> bscan -> bucket -> finalize (src stored
//     as BYTE offsets, src*256)
//   Wc[i] = theta_i*conv_w[i] + (1-theta_i)*I  (absorbs identity-mapping mix)
//   h0 = x@W_in + b_in (fp16)
//   8x fused layer: wave-per-row CSR gather -> support -> LDS -> @Wc -> relu -> fp16
//   out = h@W_out + b_out
// R10: revert R9's vector csr loads (regression: moved csr off the scalar/SMEM
// path onto VMEM, SGPR 64->32, +17% time). Restore R8's wave-uniform csr loads
// (s_load, lgkmcnt) + cndmask select; KEEP byte-offset src + pk_fma (phases A+B).

constexpr int NN = 100000;
constexpr int EE = 3200000;
constexpr int NB = 256;          // buckets, dst>>9 (512 nodes each)
constexpr int NBUCK = (NN + 511) / 512;

struct alignas(8) Half4 { __half2 lo, hi; };
typedef float f32x2 __attribute__((ext_vector_type(2)));

// ---------------- k1: bucket histogram (LDS-aggregated) ----------------
__global__ __launch_bounds__(256) void bhist_kernel(const int* __restrict__ dst,
                                                    int* __restrict__ bhist, int e) {
    __shared__ int lh[NB];
    lh[threadIdx.x] = 0;
    __syncthreads();
    for (int i = blockIdx.x * 256 + threadIdx.x; i < e; i += gridDim.x * 256)
        atomicAdd(&lh[dst[i] >> 9], 1);
    __syncthreads();
    if (lh[threadIdx.x]) atomicAdd(&bhist[threadIdx.x], lh[threadIdx.x]);
}

// ---------------- k2: bucket scan ----------------
__global__ void bscan_kernel(const int* __restrict__ bhist, int* __restrict__ bbase,
                             int* __restrict__ bcur, int* __restrict__ row_ptr) {
    if (threadIdx.x == 0) {
        int s = 0;
        for (int b = 0; b < NB; ++b) { bbase[b] = s; bcur[b] = s; s += bhist[b]; }
        bbase[NB] = s;
        row_ptr[NN] = s;
    }
}

// ---------------- k3: chunk counting-sort into buckets ----------------
__global__ __launch_bounds__(256, 3) void bucket_kernel(const int* __restrict__ src,
                                                        const int* __restrict__ dst,
                                                        const float* __restrict__ val,
                                                        int* __restrict__ bcur,
                                                        int2* __restrict__ bsorted,
                                                        int* __restrict__ bdst, int e_total) {
    __shared__ int bin_cnt[NB], bin_excl[NB], bin_gbase[NB], bin_cur[NB];
    __shared__ int2 s_ed[4096];   // 32KB
    __shared__ int  s_dp[4096];   // 16KB
    const int tid = threadIdx.x;
    const int e_base = blockIdx.x * 4096;
    const int count = min(4096, e_total - e_base);
    bin_cnt[tid] = 0;
    __syncthreads();
    #pragma unroll
    for (int i = 0; i < 16; ++i) {
        int idx = e_base + i * 256 + tid;
        if (idx < e_total) atomicAdd(&bin_cnt[dst[idx] >> 9], 1);
    }
    __syncthreads();
    if (tid == 0) {
        int s = 0;
        for (int b = 0; b < NB; ++b) { bin_excl[b] = s; s += bin_cnt[b]; }
    }
    __syncthreads();
    bin_gbase[tid] = atomicAdd(&bcur[tid], bin_cnt[tid]);
    bin_cur[tid] = bin_excl[tid];
    __syncthreads();
    #pragma unroll
    for (int i = 0; i < 16; ++i) {
        int idx = e_base + i * 256 + tid;
        if (idx < e_total) {
            int d = dst[idx];
            int pos = atomicAdd(&bin_cur[d >> 9], 1);
            s_ed[pos] = make_int2(src[idx], __float_as_int(val[idx]));
            s_dp[pos] = d;
        }
    }
    __syncthreads();
    for (int pos = tid; pos < count; pos += 256) {
        int d = s_dp[pos], b = d >> 9;
        int g = bin_gbase[b] + (pos - bin_excl[b]);
        bsorted[g] = s_ed[pos];
        bdst[g] = d;
    }
}

// ---------------- k4: per-bucket finalize (row_ptr + csr, src -> byte off) ----
__global__ __launch_bounds__(512) void finalize_kernel(const int2* __restrict__ bsorted,
                                                       const int* __restrict__ bdst,
                                                       const int* __restrict__ bbase,
                                                       int* __restrict__ row_ptr,
                                                       int2* __restrict__ csr) {
    __shared__ int hist[512], cur[512], wsum[8];
    const int tid = threadIdx.x, lane = tid & 63, wid = tid >> 6;
    const int b = blockIdx.x;
    const int n0 = b << 9;
    const int nodes = min(512, NN - n0);
    const int es = bbase[b], ee = bbase[b + 1], cnt = ee - es;
    hist[tid] = 0;
    __syncthreads();
    for (int i = tid; i < cnt; i += 512) atomicAdd(&hist[bdst[es + i] - n0], 1);
    __syncthreads();
    int v = hist[tid];
    int x = v;
    #pragma unroll
    for (int d = 1; d < 64; d <<= 1) {
        int y = __shfl_up(x, (unsigned)d);
        if (lane >= d) x += y;
    }
    if (lane == 63) wsum[wid] = x;
    __syncthreads();
    if (tid == 0) {
        int s = 0;
        for (int w = 0; w < 8; ++w) { int t2 = wsum[w]; wsum[w] = s; s += t2; }
    }
    __syncthreads();
    int excl = x - v + wsum[wid];
    cur[tid] = excl;
    if (tid < nodes) row_ptr[n0 + tid] = es + excl;
    __syncthreads();
    for (int i = tid; i < cnt; i += 512) {
        int d = bdst[es + i];
        int p = atomicAdd(&cur[d - n0], 1);
        int2 ev = bsorted[es + i];
        ev.x <<= 8;                       // src row -> byte offset (256 B/row fp16)
        csr[es + p] = ev;
    }
}

// ---------------- Wc = theta*W + (1-theta)*I ----------------
__global__ void prep_wc_kernel(const float* __restrict__ conv_w, float* __restrict__ Wc) {
    int layer = blockIdx.y;
    int idx = blockIdx.x * 256 + threadIdx.x;          // 0..16383
    float theta = logf(0.5f / (float)(layer + 1) + 1.0f);
    int k = idx >> 7, j = idx & 127;
    float w = conv_w[layer * 16384 + idx];
    Wc[layer * 16384 + idx] = theta * w + ((k == j) ? (1.0f - theta) : 0.0f);
}

// ---------------- fc_in: h0 = x@W_in + b_in (fp16 out) ----------------
__global__ __launch_bounds__(256, 2) void fc_in_kernel(const float* __restrict__ x,
                                                       const float* __restrict__ W,
                                                       const float* __restrict__ b,
                                                       __half* __restrict__ h0) {
    __shared__ float sW[128 * 128];   // 64KB
    __shared__ float sA[32 * 128];    // 16KB
    const int tid = threadIdx.x;
    #pragma unroll
    for (int t = 0; t < 16; ++t)
        ((float4*)sW)[t * 256 + tid] = ((const float4*)W)[t * 256 + tid];
    const float4* xs = (const float4*)(x + (size_t)blockIdx.x * 32 * 128);
    #pragma unroll
    for (int t = 0; t < 4; ++t)
        ((float4*)sA)[t * 256 + tid] = xs[t * 256 + tid];
    __syncthreads();

    const int rowg = tid >> 5, colg = tid & 31;
    float4 bias = ((const float4*)b)[colg];
    float acc[4][4];
    #pragma unroll
    for (int r = 0; r < 4; ++r) { acc[r][0] = bias.x; acc[r][1] = bias.y; acc[r][2] = bias.z; acc[r][3] = bias.w; }

    for (int k = 0; k < 128; ++k) {
        float4 w = *(const float4*)&sW[k * 128 + (colg << 2)];
        float s[4];
        #pragma unroll
        for (int r = 0; r < 4; ++r) s[r] = sA[((rowg << 2) + r) * 128 + k];
        #pragma unroll
        for (int r = 0; r < 4; ++r) {
            acc[r][0] = fmaf(s[r], w.x, acc[r][0]);
            acc[r][1] = fmaf(s[r], w.y, acc[r][1]);
            acc[r][2] = fmaf(s[r], w.z, acc[r][2]);
            acc[r][3] = fmaf(s[r], w.w, acc[r][3]);
        }
    }
    const int row0 = blockIdx.x * 32;
    #pragma unroll
    for (int r = 0; r < 4; ++r) {
        Half4 o;
        o.lo = __floats2half2_rn(acc[r][0], acc[r][1]);
        o.hi = __floats2half2_rn(acc[r][2], acc[r][3]);
        *(Half4*)(h0 + ((size_t)(row0 + (rowg << 2) + r) << 7) + (colg << 2)) = o;
    }
}

#define FMA4(A0, A1, PV, G) { \
    float v_ = __int_as_float((PV).y); \
    f32x2 vv_ = {v_, v_}; \
    float2 lo_ = __half22float2((G).lo), hi_ = __half22float2((G).hi); \
    f32x2 gl_ = {lo_.x, lo_.y}, gh_ = {hi_.x, hi_.y}; \
    A0 += vv_ * gl_; \
    A1 += vv_ * gh_; }

// ---------------- fused layer ----------------
// Phase A: one wave per row; csr read at wave-uniform indices (scalar s_load
//          path, lgkmcnt) then cndmask-selected per half-wave; 2 edges per
//          gather instr (half-wave x Half4/lane), 16 edges in flight,
//          byte-offset src, v_pk_fma_f32 accum, shfl-combine.
// Phase B: S (LDS fp32, 16KB) @ Wc (global fp32, L2-hot, pk_fma) -> relu -> fp16.
__global__ __launch_bounds__(256, 8) void layer_kernel(const __half* __restrict__ h,
                                                       const __half* __restrict__ h0,
                                                       const int2* __restrict__ csr,
                                                       const int* __restrict__ row_ptr,
                                                       const float* __restrict__ Wc,
                                                       __half* __restrict__ hn) {
    __shared__ float sS[32 * 128];    // 16KB
    const int tid = threadIdx.x;
    const int wid = tid >> 6, lane = tid & 63;
    const int sub = lane >> 5;              // which edge of the pair
    const int q4 = (lane & 31) << 2;        // half index within the 128-wide row
    const int q4b = q4 << 1;                // byte offset of the Half4
    const char* hb = (const char*)h;
    const char* h0b = (const char*)h0;
    const int row0 = blockIdx.x * 32;
    const int rb = __builtin_amdgcn_readfirstlane(row0 + wid * 8);

    for (int rr = 0; rr < 8; ++rr) {
        const int r = rb + rr;
        const int e0 = row_ptr[r], e1 = row_ptr[r + 1];
        f32x2 aA0 = {0.f, 0.f}, aA1 = {0.f, 0.f};
        f32x2 aB0 = {0.f, 0.f}, aB1 = {0.f, 0.f};
        int e = e0;
        for (; e + 16 <= e1; e += 16) {
            // wave-uniform csr loads -> scalar path (s_load), like R8
            int2 c0 = csr[e + 0],  c1 = csr[e + 1],  c2 = csr[e + 2],  c3 = csr[e + 3];
            int2 c4 = csr[e + 4],  c5 = csr[e + 5],  c6 = csr[e + 6],  c7 = csr[e + 7];
            int2 c8 = csr[e + 8],  c9 = csr[e + 9],  c10 = csr[e + 10], c11 = csr[e + 11];
            int2 c12 = csr[e + 12], c13 = csr[e + 13], c14 = csr[e + 14], c15 = csr[e + 15];
            int2 p0 = sub ? c1 : c0;
            int2 p1 = sub ? c3 : c2;
            int2 p2 = sub ? c5 : c4;
            int2 p3 = sub ? c7 : c6;
            int2 p4 = sub ? c9 : c8;
            int2 p5 = sub ? c11 : c10;
            int2 p6 = sub ? c13 : c12;
            int2 p7 = sub ? c15 : c14;
            Half4 g0 = *(const Half4*)(hb + (unsigned)(p0.x + q4b));
            Half4 g1 = *(const Half4*)(hb + (unsigned)(p1.x + q4b));
            Half4 g2 = *(const Half4*)(hb + (unsigned)(p2.x + q4b));
            Half4 g3 = *(const Half4*)(hb + (unsigned)(p3.x + q4b));
            Half4 g4 = *(const Half4*)(hb + (unsigned)(p4.x + q4b));
            Half4 g5 = *(const Half4*)(hb + (unsigned)(p5.x + q4b));
            Half4 g6 = *(const Half4*)(hb + (unsigned)(p6.x + q4b));
            Half4 g7 = *(const Half4*)(hb + (unsigned)(p7.x + q4b));
            FMA4(aA0, aA1, p0, g0); FMA4(aB0, aB1, p1, g1);
            FMA4(aA0, aA1, p2, g2); FMA4(aB0, aB1, p3, g3);
            FMA4(aA0, aA1, p4, g4); FMA4(aB0, aB1, p5, g5);
            FMA4(aA0, aA1, p6, g6); FMA4(aB0, aB1, p7, g7);
        }
        if (e < e1) {                       // one masked 16-wide tail block
            #pragma unroll
            for (int k = 0; k < 8; ++k) {
                int iL = e + 2 * k;
                int2 cl = csr[(iL < e1) ? iL : (e1 - 1)];
                int2 ch = csr[(iL + 1 < e1) ? (iL + 1) : (e1 - 1)];
                int2 p = sub ? ch : cl;
                if (iL + sub >= e1) p.y = 0;   // zero weight, keep clamped (valid) src
                Half4 g = *(const Half4*)(hb + (unsigned)(p.x + q4b));
                if (k & 1) { FMA4(aB0, aB1, p, g); }
                else       { FMA4(aA0, aA1, p, g); }
            }
        }
        f32x2 a0 = aA0 + aB0, a1 = aA1 + aB1;
        float4 acc = make_float4(a0.x, a0.y, a1.x, a1.y);
        acc.x += __shfl_xor(acc.x, 32);
        acc.y += __shfl_xor(acc.y, 32);
        acc.z += __shfl_xor(acc.z, 32);
        acc.w += __shfl_xor(acc.w, 32);
        if (sub == 0) {
            Half4 q = *(const Half4*)(h0b + ((size_t)r << 8) + q4b);
            float2 a = __half22float2(q.lo), c = __half22float2(q.hi);
            float4 sv;
            sv.x = 0.9f * acc.x + 0.1f * a.x;
            sv.y = 0.9f * acc.y + 0.1f * a.y;
            sv.z = 0.9f * acc.z + 0.1f * c.x;
            sv.w = 0.9f * acc.w + 0.1f * c.y;
            *(float4*)&sS[(wid * 8 + rr) * 128 + q4] = sv;
        }
    }
    __syncthreads();

    // Phase B: out = S @ Wc, relu, fp16 store. Wc from global (64KB, L1/L2-hot).
    const int rowg = tid >> 5, colg = tid & 31;
    const float* wp = Wc + (colg << 2);
    f32x2 acc2[4][2] = {};
    for (int k = 0; k < 128; k += 2) {
        float4 w0 = *(const float4*)(wp + ((size_t)k << 7));
        float4 w1 = *(const float4*)(wp + ((size_t)(k + 1) << 7));
        f32x2 w0a = {w0.x, w0.y}, w0b = {w0.z, w0.w};
        f32x2 w1a = {w1.x, w1.y}, w1b = {w1.z, w1.w};
        #pragma unroll
        for (int r = 0; r < 4; ++r) {
            float s0 = sS[((rowg << 2) + r) * 128 + k];
            float s1 = sS[((rowg << 2) + r) * 128 + k + 1];
            f32x2 s0v = {s0, s0}, s1v = {s1, s1};
            acc2[r][0] += s0v * w0a;
            acc2[r][1] += s0v * w0b;
            acc2[r][0] += s1v * w1a;
            acc2[r][1] += s1v * w1b;
        }
    }
    #pragma unroll
    for (int r = 0; r < 4; ++r) {
        Half4 o;
        o.lo = __floats2half2_rn(fmaxf(acc2[r][0].x, 0.f), fmaxf(acc2[r][0].y, 0.f));
        o.hi = __floats2half2_rn(fmaxf(acc2[r][1].x, 0.f), fmaxf(acc2[r][1].y, 0.f));
        *(Half4*)(hn + ((size_t)(row0 + (rowg << 2) + r) << 7) + (colg << 2)) = o;
    }
}

// ---------------- fc_out: out = h(fp16)@W_out + b_out ----------------
__global__ __launch_bounds__(256, 3) void fc_out_kernel(const __half* __restrict__ h,
                                                        const float* __restrict__ W,
                                                        const float* __restrict__ b,
                                                        float* __restrict__ out, int n) {
    __shared__ float sW[128 * 40];    // 20KB
    __shared__ float sA[64 * 128];    // 32KB
    const int tid = threadIdx.x;
    #pragma unroll
    for (int t = 0; t < 5; ++t)
        ((float4*)sW)[t * 256 + tid] = ((const float4*)W)[t * 256 + tid];
    const int row0 = blockIdx.x * 64;
    #pragma unroll
    for (int t = 0; t < 8; ++t) {
        int idx = t * 256 + tid;              // 4-half chunk index, 2048 total
        int row = idx >> 5;                   // 32 chunks per 128-feat row
        int gr = row0 + row;
        float4 v = make_float4(0.f, 0.f, 0.f, 0.f);
        if (gr < n) {
            Half4 q = *(const Half4*)(h + ((size_t)gr << 7) + ((idx & 31) << 2));
            float2 a = __half22float2(q.lo), c = __half22float2(q.hi);
            v = make_float4(a.x, a.y, c.x, c.y);
        }
        *(float4*)&sA[row * 128 + ((idx & 31) << 2)] = v;
    }
    __syncthreads();

    const int rowg = tid >> 3;   // 32 groups x 2 rows
    const int colg = tid & 7;    // 8 groups x 5 cols
    float acc[2][5];
    #pragma unroll
    for (int c = 0; c < 5; ++c) {
        float bb = b[colg * 5 + c];
        acc[0][c] = bb; acc[1][c] = bb;
    }
    for (int k = 0; k < 128; ++k) {
        float s0 = sA[(rowg * 2 + 0) * 128 + k];
        float s1 = sA[(rowg * 2 + 1) * 128 + k];
        #pragma unroll
        for (int c = 0; c < 5; ++c) {
            float w = sW[k * 40 + colg * 5 + c];
            acc[0][c] = fmaf(s0, w, acc[0][c]);
            acc[1][c] = fmaf(s1, w, acc[1][c]);
        }
    }
    #pragma unroll
    for (int rr = 0; rr < 2; ++rr) {
        int r = row0 + rowg * 2 + rr;
        if (r < n) {
            #pragma unroll
            for (int c = 0; c < 5; ++c)
                out[(size_t)r * 40 + colg * 5 + c] = acc[rr][c];
        }
    }
}

extern "C" void kernel_launch(void* const* d_in, const int* in_sizes, int n_in,
                              void* d_out, int out_size, void* d_ws, size_t ws_size,
                              hipStream_t stream) {
    const float* x      = (const float*)d_in[0];
    const int*   esrc   = (const int*)d_in[1];
    const int*   edst   = (const int*)d_in[2];
    const float* eval   = (const float*)d_in[3];
    const float* W_in   = (const float*)d_in[4];
    const float* b_in   = (const float*)d_in[5];
    const float* conv_w = (const float*)d_in[6];
    const float* W_out  = (const float*)d_in[7];
    const float* b_out  = (const float*)d_in[8];
    float* out = (float*)d_out;

    // workspace carve-up (~142 MB total)
    __half* h0     = (__half*)d_ws;
    __half* hA     = h0 + (size_t)NN * 128;
    __half* hB     = hA + (size_t)NN * 128;
    float*  Wc     = (float*)(hB + (size_t)NN * 128);
    int*   row_ptr = (int*)(Wc + 8 * 128 * 128);          // NN+2 ints
    int*   bhist   = row_ptr + (NN + 2);                  // 256
    int*   bbase   = bhist + NB;                          // NB+1 (padded even)
    int*   bcur    = bbase + (NB + 2);                    // 256
    int2*  csr     = (int2*)(bcur + NB);                  // EE int2 (8B-aligned)
    int2*  bsorted = csr + EE;                            // EE int2
    int*   bdst    = (int*)(bsorted + EE);                // EE ints

    // --- CSR build (bucket-local) ---
    hipMemsetAsync(bhist, 0, NB * sizeof(int), stream);
    bhist_kernel<<<1024, 256, 0, stream>>>(edst, bhist, EE);
    bscan_kernel<<<1, 64, 0, stream>>>(bhist, bbase, bcur, row_ptr);
    bucket_kernel<<<(EE + 4095) / 4096, 256, 0, stream>>>(esrc, edst, eval, bcur,
                                                          bsorted, bdst, EE);
    finalize_kernel<<<NBUCK, 512, 0, stream>>>(bsorted, bdst, bbase, row_ptr, csr);

    // --- weights prep ---
    prep_wc_kernel<<<dim3(64, 8), 256, 0, stream>>>(conv_w, Wc);

    // --- fc_in ---
    fc_in_kernel<<<NN / 32, 256, 0, stream>>>(x, W_in, b_in, h0);

    // --- 8 fused layers, ping-pong hA/hB ---
    const __half* hin = h0;
    __half* hout = hA;
    for (int i = 0; i < 8; ++i) {
        layer_kernel<<<NN / 32, 256, 0, stream>>>(hin, h0, csr, row_ptr, Wc + i * 16384, hout);
        hin = hout;
        hout = (hout == hA) ? hB : hA;
    }

    // --- fc_out ---
    fc_out_kernel<<<(NN + 63) / 64, 256, 0, stream>>>(hin, W_out, b_out, out, NN);
}